// Round 3
// baseline (113.459 us; speedup 1.0000x reference)
//
#include <hip/hip_runtime.h>

#define CIN 64
#define HH 32
#define WW 32

__device__ __forceinline__ float fexp2(float x) {
#if __has_builtin(__builtin_amdgcn_exp2f)
    return __builtin_amdgcn_exp2f(x);   // v_exp_f32
#else
    return exp2f(x);
#endif
}
__device__ __forceinline__ float flog2(float x) {
#if __has_builtin(__builtin_amdgcn_logf)
    return __builtin_amdgcn_logf(x);    // v_log_f32 (log2)
#else
    return log2f(x);
#endif
}

// out[n,o,ho,wo] = OS * sum_{c,k} [ log2(1+2^z)^2 - log2(1+C2*2^z)^2 ],
//   z = (x[n,c,ho+di-1,wo+dj-1] - theta[o,c,k]) * SZ   (zero-padded x)
//   SZ = log2(e)/phi, C2 = exp(-VD/phi), OS = ln2^2 * ALPHA * tia_gain
//
// 1 output channel per thread: 262144 threads = 4096 waves = 16 waves/CU
// (4 waves/SIMD) -- grid was the occupancy cap at 2 o/thread (R2 post-mortem).
__global__ __launch_bounds__(256) void ekv_kernel(
        const float* __restrict__ x, const float* __restrict__ theta,
        float* __restrict__ out) {
    constexpr float SZ = 19.235933878519512f;    // log2(e)/0.075
    constexpr float C2 = 1.2726342e-3f;          // exp(-0.5/0.075)
    constexpr float OS = 0.020018875579925058f;  // ln2^2 * 2e-6 * 500000/24

    const int t  = threadIdx.x;
    const int wo = t & 31;              // 32-wide rows -> coalesced
    const int hr = t >> 5;              // 0..7
    const int ho = (int)blockIdx.y * 8 + hr;
    const int n  = (int)blockIdx.z;
    const int o  = (int)blockIdx.x;     // 1 output channel per thread

    const float* xb = x + n * (CIN * HH * WW);
    const float* w0 = theta + o * (CIN * 9);

    // 9 taps: branch-free zero padding via clamped offset + mask (mask holds SZ)
    int   off[9];
    float msk[9];
#pragma unroll
    for (int di = 0; di < 3; ++di) {
#pragma unroll
        for (int dj = 0; dj < 3; ++dj) {
            int h = ho + di - 1, w = wo + dj - 1;
            bool v = (h >= 0) && (h < HH) && (w >= 0) && (w < WW);
            int hc = min(max(h, 0), HH - 1);
            int wc = min(max(w, 0), WW - 1);
            off[di * 3 + dj] = hc * WW + wc;
            msk[di * 3 + dj] = v ? SZ : 0.0f;  // padded x == 0 -> xs == 0
        }
    }

    float af = 0.f, ar = 0.f;

    for (int c = 0; c < CIN; ++c) {
        const float* xc = xb + c * (HH * WW);
        float xs[9];
#pragma unroll
        for (int k = 0; k < 9; ++k) xs[k] = xc[off[k]] * msk[k];

        const float* wc = w0 + c * 9;   // wave-uniform -> scalar loads
#pragma unroll
        for (int k = 0; k < 9; ++k) {
            float z  = fmaf(wc[k], -SZ, xs[k]);  // (x - w) * SZ
            float tt = fexp2(z);
            float f  = flog2(1.0f + tt);
            float r  = flog2(fmaf(C2, tt, 1.0f));
            af = fmaf(f, f, af);
            ar = fmaf(r, r, ar);
        }
    }

    out[((n * 64 + o) * HH + ho) * WW + wo] = (af - ar) * OS;
}

extern "C" void kernel_launch(void* const* d_in, const int* in_sizes, int n_in,
                              void* d_out, int out_size, void* d_ws, size_t ws_size,
                              hipStream_t stream) {
    const float* x     = (const float*)d_in[0];   // (4,64,32,32) fp32
    const float* theta = (const float*)d_in[1];   // (64,64,3,3) fp32
    float* out = (float*)d_out;                   // (4,64,32,32) fp32

    dim3 grid(64, 4, 4);   // o, ho-tiles(8 rows), n
    dim3 block(256);
    ekv_kernel<<<grid, block, 0, stream>>>(x, theta, out);
}

// Round 4
// 106.172 us; speedup vs baseline: 1.0686x; 1.0686x over previous
//
#include <hip/hip_runtime.h>
#include <math.h>

#define CIN 64
#define HH 32
#define WW 32

// out[n,o,ho,wo] = OS * sum_{c,k} g(z),  z = (x - theta)*SZ  (zero-padded x)
// g(z) = log2(1+2^z)^2 - log2(1+2^(z-D2))^2, evaluated via a 1024-entry
// piecewise-linear LUT in LDS over z in [-32,32), h = 1/16.
//   - below -32: entry 0 line ~ (0,0)  -> g ~ 0 (true: < 1e-17)
//   - above +32: last entry's line == exact asymptote 2*D2*z - D2^2 (to ~1e-3)
// so index clamping alone handles both tails, no branches.
// SZ = log2(e)/phi, D2 = VD/(phi*ln2), OS = ln2^2 * ALPHA * tia_gain

#define LUT_N    1024
#define LUT_H    0.0625
#define LUT_ZMIN (-32.0)

__global__ __launch_bounds__(256) void ekv_kernel(
        const float* __restrict__ x, const float* __restrict__ theta,
        float* __restrict__ out) {
    constexpr float SZ = 19.235933878519512f;    // log2(e)/0.075
    constexpr double D2 = 9.6179661929342026;    // 0.5/(0.075*ln2)
    constexpr float OS = 0.020018875579925058f;  // ln2^2 * 2e-6 * 500000/24

    __shared__ float2 lut[LUT_N];

    const int t = threadIdx.x;

    // ---- build LUT (once per block; 4 entries/thread, double precision) ----
    for (int i = t; i < LUT_N; i += 256) {
        double z0 = LUT_ZMIN + (double)i * LUT_H;
        double z1 = z0 + LUT_H;
        // g(z) in log2 domain
        double t0 = exp2(z0), t1 = exp2(z1);
        double f0 = log2(1.0 + t0), f1 = log2(1.0 + t1);
        double r0 = log2(1.0 + exp2(z0 - D2)), r1 = log2(1.0 + exp2(z1 - D2));
        double g0 = f0 * f0 - r0 * r0;
        double g1 = f1 * f1 - r1 * r1;
        double s  = (g1 - g0) * (1.0 / LUT_H);
        double b  = g0 - s * z0;
        lut[i] = make_float2((float)s, (float)b);
    }
    __syncthreads();

    const int wo = t & 31;              // 32-wide rows -> coalesced
    const int hr = t >> 5;              // 0..7
    const int ho = (int)blockIdx.y * 8 + hr;
    const int n  = (int)blockIdx.z;
    const int o  = (int)blockIdx.x;     // 1 output channel per thread

    const float* xb = x + n * (CIN * HH * WW);
    const float* w0 = theta + o * (CIN * 9);

    // 9 taps: branch-free zero padding via clamped offset + mask (mask holds SZ)
    // pad contributes g(-w*SZ) == mask path since xs becomes 0 there.
    int   off[9];
    float msk[9];
#pragma unroll
    for (int di = 0; di < 3; ++di) {
#pragma unroll
        for (int dj = 0; dj < 3; ++dj) {
            int h = ho + di - 1, w = wo + dj - 1;
            bool v = (h >= 0) && (h < HH) && (w >= 0) && (w < WW);
            int hc = min(max(h, 0), HH - 1);
            int wc = min(max(w, 0), WW - 1);
            off[di * 3 + dj] = hc * WW + wc;
            msk[di * 3 + dj] = v ? SZ : 0.0f;
        }
    }

    float accS = 0.f, accB = 0.f;   // sum of s*z and b separately (2 fmas/pair)

    for (int c = 0; c < CIN; ++c) {
        const float* xc = xb + c * (HH * WW);
        float xs[9];
#pragma unroll
        for (int k = 0; k < 9; ++k) xs[k] = xc[off[k]] * msk[k];

        const float* wc = w0 + c * 9;   // wave-uniform -> scalar loads
#pragma unroll
        for (int k = 0; k < 9; ++k) {
            float z  = fmaf(wc[k], -SZ, xs[k]);          // (x - w) * SZ
            float tf = fmaf(z, 16.0f, 512.0f);           // (z - zmin)/h
            tf = fminf(fmaxf(tf, 0.0f), 1023.0f);        // v_med3_f32
            unsigned idx = (unsigned)tf;
            float2 sb = lut[idx];                        // ds_read_b64
            accS = fmaf(sb.x, z, accS);
            accB += sb.y;
        }
    }

    out[((n * 64 + o) * HH + ho) * WW + wo] = (accS + accB) * OS;
}

extern "C" void kernel_launch(void* const* d_in, const int* in_sizes, int n_in,
                              void* d_out, int out_size, void* d_ws, size_t ws_size,
                              hipStream_t stream) {
    const float* x     = (const float*)d_in[0];   // (4,64,32,32) fp32
    const float* theta = (const float*)d_in[1];   // (64,64,3,3) fp32
    float* out = (float*)d_out;                   // (4,64,32,32) fp32

    dim3 grid(64, 4, 4);   // o, ho-tiles(8 rows), n
    dim3 block(256);
    ekv_kernel<<<grid, block, 0, stream>>>(x, theta, out);
}

// Round 5
// 90.570 us; speedup vs baseline: 1.2527x; 1.1723x over previous
//
#include <hip/hip_runtime.h>
#include <math.h>

#define CIN 64
#define HH 32
#define WW 32
#define NW (64 * 64 * 9)        // theta element count
#define LUT_N 1024

// out[n,o,ho,wo] = OS * sum_{c,k} g(z),  z = (x - theta)*SZ  (zero-padded x)
// g(z) = log2(1+2^z)^2 - log2(1+2^(z-D2))^2, via piecewise-linear LUT indexed
// by t = (z+32)*16  ->  t = fma(x, 16*SZ, W) with W = 512 - 16*SZ*w precomputed
// in d_ws by a prep kernel (scalar-load path in the main loop).
// LUT entry i: line through (i,g_i),(i+1,g_{i+1}) in t-units; index clamped,
// t UNclamped in the evaluation fma -> entry0 line ~ (0,0) handles z<<-32,
// entry1023 line == exact large-z asymptote 2*D2*z - D2^2.

__global__ __launch_bounds__(256) void prep_kernel(const float* __restrict__ theta,
                                                   float* __restrict__ ws) {
    constexpr float SZ = 19.235933878519512f;    // log2(e)/0.075
    const int b = blockIdx.x;
    if (b < NW / 256) {                          // 144 blocks: weight transform
        int i = b * 256 + threadIdx.x;
        ws[i] = fmaf(theta[i], -16.0f * SZ, 512.0f);
    } else {                                     // 1 block: LUT build (double)
        const double D2 = 9.6179661929342026;    // 0.5/(0.075*ln2)
        float2* lut = (float2*)(ws + NW);
        for (int j = threadIdx.x; j < LUT_N; j += 256) {
            double z0 = -32.0 + j * 0.0625;
            double z1 = z0 + 0.0625;
            double f0 = log2(1.0 + exp2(z0)), f1 = log2(1.0 + exp2(z1));
            double r0 = log2(1.0 + exp2(z0 - D2)), r1 = log2(1.0 + exp2(z1 - D2));
            double g0 = f0 * f0 - r0 * r0;
            double g1 = f1 * f1 - r1 * r1;
            double S = g1 - g0;                  // slope per t-unit
            double B = g0 - S * (double)j;       // intercept in t-domain
            lut[j] = make_float2((float)S, (float)B);
        }
    }
}

__global__ __launch_bounds__(256) void ekv_kernel(
        const float* __restrict__ x, const float* __restrict__ ws,
        float* __restrict__ out) {
    constexpr float SZ16 = 16.0f * 19.235933878519512f;  // 16*SZ
    constexpr float OS = 0.020018875579925058f;  // ln2^2 * 2e-6 * 500000/24

    __shared__ float2 lut[LUT_N];

    const int t = threadIdx.x;
    {   // LUT: plain float2 copies from ws (built by prep kernel)
        const float2* lg = (const float2*)(ws + NW);
#pragma unroll
        for (int i = 0; i < LUT_N / 256; ++i)
            lut[t + 256 * i] = lg[t + 256 * i];
    }
    __syncthreads();

    const int wo = t & 31;              // 32-wide rows -> coalesced
    const int hr = t >> 5;              // 0..7
    const int ho = (int)blockIdx.y * 8 + hr;
    const int n  = (int)blockIdx.z;
    const int o  = (int)blockIdx.x;     // 1 output channel per thread

    const float* xb = x + n * (CIN * HH * WW);
    const float* W0 = ws + o * (CIN * 9);   // transformed weights (uniform -> s_load)

    // 9 taps: branch-free zero padding via clamped offset + tap-scale m
    // padded tap: m=0 -> t = W = 512 - 16*SZ*w  == exact x=0 contribution
    int   off[9];
    float m[9];
#pragma unroll
    for (int di = 0; di < 3; ++di) {
#pragma unroll
        for (int dj = 0; dj < 3; ++dj) {
            int h = ho + di - 1, w = wo + dj - 1;
            bool v = (h >= 0) && (h < HH) && (w >= 0) && (w < WW);
            int hc = min(max(h, 0), HH - 1);
            int wc = min(max(w, 0), WW - 1);
            off[di * 3 + dj] = hc * WW + wc;
            m[di * 3 + dj] = v ? SZ16 : 0.0f;
        }
    }

    float accS = 0.f, accB = 0.f;

#pragma unroll 2
    for (int c = 0; c < CIN; ++c) {
        const float* xc = xb + c * (HH * WW);
        float xv[9];
#pragma unroll
        for (int k = 0; k < 9; ++k) xv[k] = xc[off[k]];

        const float* Wc = W0 + c * 9;   // wave-uniform -> scalar loads
#pragma unroll
        for (int k = 0; k < 9; ++k) {
            float tt = fmaf(xv[k], m[k], Wc[k]);         // LUT coordinate
#if __has_builtin(__builtin_amdgcn_fmed3f)
            float tc = __builtin_amdgcn_fmed3f(tt, 0.0f, 1023.0f);
#else
            float tc = fminf(fmaxf(tt, 0.0f), 1023.0f);
#endif
            unsigned idx = (unsigned)tc;
            float2 sb = lut[idx];                        // ds_read_b64
            accS = fmaf(sb.x, tt, accS);                 // unclamped t: exact tails
            accB += sb.y;
        }
    }

    out[((n * 64 + o) * HH + ho) * WW + wo] = (accS + accB) * OS;
}

extern "C" void kernel_launch(void* const* d_in, const int* in_sizes, int n_in,
                              void* d_out, int out_size, void* d_ws, size_t ws_size,
                              hipStream_t stream) {
    const float* x     = (const float*)d_in[0];   // (4,64,32,32) fp32
    const float* theta = (const float*)d_in[1];   // (64,64,3,3) fp32
    float* out = (float*)d_out;                   // (4,64,32,32) fp32
    float* ws  = (float*)d_ws;                    // NW floats W + 1024 float2 LUT

    prep_kernel<<<NW / 256 + 1, 256, 0, stream>>>(theta, ws);

    dim3 grid(64, 4, 4);   // o, ho-tiles(8 rows), n
    dim3 block(256);
    ekv_kernel<<<grid, block, 0, stream>>>(x, ws, out);
}